// Round 14
// baseline (313.304 us; speedup 1.0000x reference)
//
#include <hip/hip_runtime.h>

#define N_NODES 50000
#define E_EDGES 800000
#define E_EXT   850000   // + self loops
#define IN_CH   128
#define HC      256
#define NHEAD   8
#define CH      32
#define NGRAPH  256
#define SCAN_CHUNK 1024
#define N_CHUNKS ((N_NODES + SCAN_CHUNK - 1) / SCAN_CHUNK)

typedef __bf16 bf16x8 __attribute__((ext_vector_type(8)));
typedef float  f32x4  __attribute__((ext_vector_type(4)));

__device__ inline ushort f2bf(float f) {
    union { float f; unsigned u; } v; v.f = f;
    unsigned u = v.u;
    unsigned r = u + 0x7FFFu + ((u >> 16) & 1u);
    return (ushort)(r >> 16);
}
__device__ inline float bflo(unsigned u) {
    union { unsigned u; float f; } v; v.u = u << 16; return v.f;
}
__device__ inline float bfhi(unsigned u) {
    union { unsigned u; float f; } v; v.u = u & 0xFFFF0000u; return v.f;
}

// ---- prep: W cvt + composites Vb1/Vb2 (bf16) + V3 (f32) + bw + histogram ---
// Vb1[16][128]: rows 0-7 = W1_h^T as1_h, 8-15 = W1_h^T ad1_h   (bf16)
// Vb2[16][256]: same for layer 2                                (bf16)
// V3 [24][256]: rows 0-7 = W3_h^T as3_h, 8-15 = W3_h^T Wf_h, 16-23 = W3_h^T ad3_h (f32)
#define W1_N4 (HC * IN_CH / 4)            // 8192
#define W23_N4 (HC * HC / 4)              // 16384
#define CVT_N4 (W1_N4 + 2 * W23_N4)       // 40960
#define V1_N  (16 * IN_CH)                // 2048
#define V2_N  (16 * HC)                   // 4096
#define V3_N  (24 * HC)                   // 6144
#define COMP_TOT (V1_N + V2_N + V3_N)     // 12288
#define PREP_TOT (CVT_N4 + COMP_TOT + E_EXT)
__global__ __launch_bounds__(256) void prep_kernel(
    const float* __restrict__ W1, const float* __restrict__ W2,
    const float* __restrict__ W3,
    ushort* __restrict__ W1b, ushort* __restrict__ W2b, ushort* __restrict__ W3b,
    const float* __restrict__ as1, const float* __restrict__ ad1,
    const float* __restrict__ as2, const float* __restrict__ ad2,
    const float* __restrict__ as3, const float* __restrict__ ad3,
    const float* __restrict__ b3, const float* __restrict__ Wf,
    float* __restrict__ bw,
    ushort* __restrict__ Vb1, ushort* __restrict__ Vb2, float* __restrict__ V3,
    const int* __restrict__ ei, int* __restrict__ deg)
{
    int i = blockIdx.x * blockDim.x + threadIdx.x;
    if (blockIdx.x == 0 && threadIdx.x < NHEAD) {
        float s = 0.f;
        for (int c = 0; c < CH; c++)
            s += b3[threadIdx.x * CH + c] * Wf[threadIdx.x * CH + c];
        bw[threadIdx.x] = s;
    }
    if (i < CVT_N4) {
        const float* src; ushort* dst; int k;
        if (i < W1_N4) { src = W1; dst = W1b; k = i; }
        else if (i < W1_N4 + W23_N4) { src = W2; dst = W2b; k = i - W1_N4; }
        else { src = W3; dst = W3b; k = i - W1_N4 - W23_N4; }
        float4 v = *(const float4*)(src + (size_t)k * 4);
        ushort4 o;
        o.x = f2bf(v.x); o.y = f2bf(v.y); o.z = f2bf(v.z); o.w = f2bf(v.w);
        *(ushort4*)(dst + (size_t)k * 4) = o;
        return;
    }
    int c2 = i - CVT_N4;
    if (c2 < V1_N + V2_N) {
        const float* Wsrc; const float* aw; ushort* dst; int F_, j, k;
        if (c2 < V1_N) {
            F_ = IN_CH; j = c2 >> 7; k = c2 & 127; Wsrc = W1; dst = Vb1;
            aw = (j < 8) ? as1 : ad1;
        } else {
            c2 -= V1_N;
            F_ = HC; j = c2 >> 8; k = c2 & 255; Wsrc = W2; dst = Vb2;
            aw = (j < 8) ? as2 : ad2;
        }
        int h = j & 7;
        float v = 0.f;
        for (int c = 0; c < CH; c++)
            v += aw[h * CH + c] * Wsrc[(size_t)(h * CH + c) * F_ + k];
        dst[j * F_ + k] = f2bf(v);
        return;
    }
    c2 -= V1_N + V2_N;
    if (c2 < V3_N) {
        int j = c2 >> 8, k = c2 & 255;
        int h = j & 7;
        const float* aw = (j < 8) ? as3 : (j < 16 ? Wf : ad3);
        float v = 0.f;
        for (int c = 0; c < CH; c++)
            v += aw[h * CH + c] * W3[(size_t)(h * CH + c) * HC + k];
        V3[j * HC + k] = v;
        return;
    }
    int e = i - CVT_N4 - COMP_TOT;
    if (e < E_EXT) {
        int d = (e < E_EDGES) ? ei[E_EDGES + e] : (e - E_EDGES);
        atomicAdd(&deg[d], 1);
    }
}

// ------- MFMA GEMM 128x128 tile + MFMA attention epilogue -------------------
// blockIdx.y==0 even waves also compute [rows x 16] = A @ Vb[0:16]^T:
// col fr<8 -> a_s[m][fr], fr>=8 -> a_d[m][fr-8].
__global__ __launch_bounds__(256) void mfma_gemm_kernel(
    const ushort* __restrict__ Xb, const float* __restrict__ Xf,
    const ushort* __restrict__ Wb, const ushort* __restrict__ Vb,
    ushort* __restrict__ Hb, int M, int F,
    float* __restrict__ as_out, float* __restrict__ ad_out)
{
    __shared__ ushort As[128][40];
    __shared__ ushort Bs[128][40];
    __shared__ ushort Vs[16][40];
    const int tid  = threadIdx.x;
    const int lane = tid & 63;
    const int wave = tid >> 6;
    const int wr = (wave >> 1) * 64;
    const int wc = (wave & 1) * 64;
    const int bm = blockIdx.x * 128;
    const int bn = blockIdx.y * 128;
    const int lrow = tid >> 2;
    const int lseg = (tid & 3) * 8;
    const int fr = lane & 15;
    const int fk = (lane >> 4) * 8;
    const bool doV = (blockIdx.y == 0) && !(wave & 1);

    f32x4 zero = {0.f, 0.f, 0.f, 0.f};
    f32x4 acc[4][4];
    f32x4 accv[4];
    #pragma unroll
    for (int i = 0; i < 4; i++) {
        accv[i] = zero;
        #pragma unroll
        for (int j = 0; j < 4; j++) acc[i][j] = zero;
    }

    for (int k0 = 0; k0 < F; k0 += 32) {
        #pragma unroll
        for (int rr = 0; rr < 2; rr++) {
            int row = lrow + rr * 64;
            int arow = bm + row;
            bf16x8 av = {};
            if (Xf) {
                if (arow < M) {
                    float4 lo = *(const float4*)(Xf + (size_t)arow * F + k0 + lseg);
                    float4 hi = *(const float4*)(Xf + (size_t)arow * F + k0 + lseg + 4);
                    ushort t[8] = { f2bf(lo.x), f2bf(lo.y), f2bf(lo.z), f2bf(lo.w),
                                    f2bf(hi.x), f2bf(hi.y), f2bf(hi.z), f2bf(hi.w) };
                    av = *(const bf16x8*)t;
                }
            } else {
                if (arow < M) av = *(const bf16x8*)(Xb + (size_t)arow * F + k0 + lseg);
            }
            *(bf16x8*)(&As[row][lseg]) = av;
            bf16x8 bv = *(const bf16x8*)(Wb + (size_t)(bn + row) * F + k0 + lseg);
            *(bf16x8*)(&Bs[row][lseg]) = bv;
        }
        if (tid < 64) {
            int vr = tid >> 2;
            *(bf16x8*)(&Vs[vr][lseg]) = *(const bf16x8*)(Vb + (size_t)vr * F + k0 + lseg);
        }
        __syncthreads();
        bf16x8 a[4], b[4];
        #pragma unroll
        for (int i = 0; i < 4; i++) {
            a[i] = *(const bf16x8*)(&As[wr + i * 16 + fr][fk]);
            b[i] = *(const bf16x8*)(&Bs[wc + i * 16 + fr][fk]);
        }
        #pragma unroll
        for (int i = 0; i < 4; i++)
            #pragma unroll
            for (int j = 0; j < 4; j++)
                acc[i][j] = __builtin_amdgcn_mfma_f32_16x16x32_bf16(
                    a[i], b[j], acc[i][j], 0, 0, 0);
        if (doV) {
            bf16x8 bv = *(const bf16x8*)(&Vs[fr][fk]);
            #pragma unroll
            for (int i = 0; i < 4; i++)
                accv[i] = __builtin_amdgcn_mfma_f32_16x16x32_bf16(
                    a[i], bv, accv[i], 0, 0, 0);
        }
        __syncthreads();
    }
    const int rb = (lane >> 4) * 4;
    #pragma unroll
    for (int i = 0; i < 4; i++) {
        #pragma unroll
        for (int r = 0; r < 4; r++) {
            int m = bm + wr + i * 16 + rb + r;
            if (m < M) {
                #pragma unroll
                for (int j = 0; j < 4; j++)
                    Hb[(size_t)m * HC + bn + wc + j * 16 + fr] = f2bf(acc[i][j][r]);
            }
        }
    }
    if (doV) {
        #pragma unroll
        for (int i = 0; i < 4; i++) {
            #pragma unroll
            for (int r = 0; r < 4; r++) {
                int m = bm + wr + i * 16 + rb + r;
                if (m < M) {
                    float v = accv[i][r];
                    if (fr < 8) as_out[m * NHEAD + fr] = v;
                    else        ad_out[m * NHEAD + fr - 8] = v;
                }
            }
        }
    }
}

// ---------------- CSR build ----------------
__global__ void scan1_kernel(const int* __restrict__ deg,
                             int* __restrict__ row_ptr, int* __restrict__ csum)
{
    __shared__ int buf[SCAN_CHUNK];
    int t = threadIdx.x;
    int base = blockIdx.x * SCAN_CHUNK;
    int v = (base + t < N_NODES) ? deg[base + t] : 0;
    buf[t] = v;
    __syncthreads();
    for (int off = 1; off < SCAN_CHUNK; off <<= 1) {
        int x = buf[t];
        int y = (t >= off) ? buf[t - off] : 0;
        __syncthreads();
        buf[t] = x + y;
        __syncthreads();
    }
    if (base + t < N_NODES) row_ptr[base + t] = buf[t] - v;
    if (t == SCAN_CHUNK - 1) csum[blockIdx.x] = buf[t];
}

__global__ __launch_bounds__(256) void scan23_kernel(
    int* __restrict__ row_ptr, const int* __restrict__ csum)
{
    __shared__ int pref[64];
    int t = threadIdx.x;
    int i = blockIdx.x * blockDim.x + t;
    if (t < 64) pref[t] = (t < N_CHUNKS) ? csum[t] : 0;
    __syncthreads();
    for (int off = 1; off < 64; off <<= 1) {
        int x = 0, y = 0;
        if (t < 64) { x = pref[t]; y = (t >= off) ? pref[t - off] : 0; }
        __syncthreads();
        if (t < 64) pref[t] = x + y;   // inclusive
        __syncthreads();
    }
    if (i < N_NODES) {
        int ch = i / SCAN_CHUNK;
        row_ptr[i] += (ch > 0) ? pref[ch - 1] : 0;
    }
    if (i == 0) row_ptr[N_NODES] = E_EXT;
}

__global__ __launch_bounds__(256) void scatter_kernel(
    const int* __restrict__ ei, const int* __restrict__ row_ptr,
    int* __restrict__ cur, int* __restrict__ esrc)
{
    int eid = blockIdx.x * blockDim.x + threadIdx.x;
    if (eid >= E_EXT) return;
    int s, d;
    if (eid < E_EDGES) { s = ei[eid]; d = ei[E_EDGES + eid]; }
    else { s = eid - E_EDGES; d = s; }
    int pos = row_ptr[d] + atomicAdd(&cur[d], 1);
    esrc[pos] = s;
}

// ------- heavy gather: 2 dst/wave, 8 ch/lane, 4-deep pipeline ---------------
// out_b != null (layer 1): write bf16 row.
// V3 != null (layer 2): fused layer-3 coefficients via full-256 composite dots:
//   out j<8 -> q[n][j].x, j<16 -> q[n][j-8].y, j<24 -> ad3_out[n][j-16]
__global__ __launch_bounds__(256) void gather_kernel(
    const int* __restrict__ row_ptr, const int* __restrict__ esrc,
    const ushort* __restrict__ hb,
    const float* __restrict__ a_s, const float* __restrict__ a_d,
    const float* __restrict__ bias,
    ushort* __restrict__ out_b,
    const float* __restrict__ V3,
    float2* __restrict__ q_out, float* __restrict__ ad3_out)
{
    int wv = (blockIdx.x * blockDim.x + threadIdx.x) >> 6;
    int lane = threadIdx.x & 63;
    int half = lane >> 5;
    int lloc = lane & 31;
    int n = wv * 2 + half;
    if (n >= N_NODES) return;
    const int hh = lloc >> 2;
    const int shbase = half << 5;
    const float adv = a_d[n * NHEAD + hh];
    const int beg = row_ptr[n], end = row_ptr[n + 1];

    float a0=0.f,a1=0.f,a2=0.f,a3=0.f,a4=0.f,a5=0.f,a6=0.f,a7=0.f,den=0.f;

    for (int base = beg; base < end; base += 32) {
        int cnt = min(32, end - base);
        int sv = (base + lloc < end) ? esrc[base + lloc] : 0;
        int j = 0;
        for (; j + 4 <= cnt; j += 4) {
            int s0 = __shfl(sv, shbase + j);
            int s1 = __shfl(sv, shbase + j + 1);
            int s2 = __shfl(sv, shbase + j + 2);
            int s3 = __shfl(sv, shbase + j + 3);
            float e0 = a_s[s0 * NHEAD + hh];
            float e1 = a_s[s1 * NHEAD + hh];
            float e2 = a_s[s2 * NHEAD + hh];
            float e3 = a_s[s3 * NHEAD + hh];
            uint4 u0 = *(const uint4*)(hb + (size_t)s0 * HC + lloc * 8);
            uint4 u1 = *(const uint4*)(hb + (size_t)s1 * HC + lloc * 8);
            uint4 u2 = *(const uint4*)(hb + (size_t)s2 * HC + lloc * 8);
            uint4 u3 = *(const uint4*)(hb + (size_t)s3 * HC + lloc * 8);
            e0 += adv; e0 = (e0 > 0.f) ? e0 : 0.2f * e0; float w0 = __expf(e0);
            e1 += adv; e1 = (e1 > 0.f) ? e1 : 0.2f * e1; float w1 = __expf(e1);
            e2 += adv; e2 = (e2 > 0.f) ? e2 : 0.2f * e2; float w2 = __expf(e2);
            e3 += adv; e3 = (e3 > 0.f) ? e3 : 0.2f * e3; float w3 = __expf(e3);
            den += (w0 + w1) + (w2 + w3);
            a0 = fmaf(w0, bflo(u0.x), a0); a1 = fmaf(w0, bfhi(u0.x), a1);
            a2 = fmaf(w0, bflo(u0.y), a2); a3 = fmaf(w0, bfhi(u0.y), a3);
            a4 = fmaf(w0, bflo(u0.z), a4); a5 = fmaf(w0, bfhi(u0.z), a5);
            a6 = fmaf(w0, bflo(u0.w), a6); a7 = fmaf(w0, bfhi(u0.w), a7);
            a0 = fmaf(w1, bflo(u1.x), a0); a1 = fmaf(w1, bfhi(u1.x), a1);
            a2 = fmaf(w1, bflo(u1.y), a2); a3 = fmaf(w1, bfhi(u1.y), a3);
            a4 = fmaf(w1, bflo(u1.z), a4); a5 = fmaf(w1, bfhi(u1.z), a5);
            a6 = fmaf(w1, bflo(u1.w), a6); a7 = fmaf(w1, bfhi(u1.w), a7);
            a0 = fmaf(w2, bflo(u2.x), a0); a1 = fmaf(w2, bfhi(u2.x), a1);
            a2 = fmaf(w2, bflo(u2.y), a2); a3 = fmaf(w2, bfhi(u2.y), a3);
            a4 = fmaf(w2, bflo(u2.z), a4); a5 = fmaf(w2, bfhi(u2.z), a5);
            a6 = fmaf(w2, bflo(u2.w), a6); a7 = fmaf(w2, bfhi(u2.w), a7);
            a0 = fmaf(w3, bflo(u3.x), a0); a1 = fmaf(w3, bfhi(u3.x), a1);
            a2 = fmaf(w3, bflo(u3.y), a2); a3 = fmaf(w3, bfhi(u3.y), a3);
            a4 = fmaf(w3, bflo(u3.z), a4); a5 = fmaf(w3, bfhi(u3.z), a5);
            a6 = fmaf(w3, bflo(u3.w), a6); a7 = fmaf(w3, bfhi(u3.w), a7);
        }
        for (; j < cnt; j++) {
            int s = __shfl(sv, shbase + j);
            float e = a_s[s * NHEAD + hh] + adv;
            e = (e > 0.f) ? e : 0.2f * e;
            float w = __expf(e);
            den += w;
            uint4 u = *(const uint4*)(hb + (size_t)s * HC + lloc * 8);
            a0 = fmaf(w, bflo(u.x), a0); a1 = fmaf(w, bfhi(u.x), a1);
            a2 = fmaf(w, bflo(u.y), a2); a3 = fmaf(w, bfhi(u.y), a3);
            a4 = fmaf(w, bflo(u.z), a4); a5 = fmaf(w, bfhi(u.z), a5);
            a6 = fmaf(w, bflo(u.w), a6); a7 = fmaf(w, bfhi(u.w), a7);
        }
    }
    float inv = 1.f / den;
    float4 ba = *(const float4*)(bias + lloc * 8);
    float4 bb = *(const float4*)(bias + lloc * 8 + 4);
    float o0 = fmaf(a0, inv, ba.x), o1 = fmaf(a1, inv, ba.y);
    float o2 = fmaf(a2, inv, ba.z), o3 = fmaf(a3, inv, ba.w);
    float o4 = fmaf(a4, inv, bb.x), o5 = fmaf(a5, inv, bb.y);
    float o6 = fmaf(a6, inv, bb.z), o7 = fmaf(a7, inv, bb.w);
    o0 = fmaxf(o0, 0.f); o1 = fmaxf(o1, 0.f); o2 = fmaxf(o2, 0.f); o3 = fmaxf(o3, 0.f);
    o4 = fmaxf(o4, 0.f); o5 = fmaxf(o5, 0.f); o6 = fmaxf(o6, 0.f); o7 = fmaxf(o7, 0.f);
    if (out_b) {
        uint4 ob;
        ob.x = (unsigned)f2bf(o0) | ((unsigned)f2bf(o1) << 16);
        ob.y = (unsigned)f2bf(o2) | ((unsigned)f2bf(o3) << 16);
        ob.z = (unsigned)f2bf(o4) | ((unsigned)f2bf(o5) << 16);
        ob.w = (unsigned)f2bf(o6) | ((unsigned)f2bf(o7) << 16);
        *(uint4*)(out_b + (size_t)n * HC + lloc * 8) = ob;
    }
    if (V3) {
        // lane lloc holds channels lloc*8..lloc*8+7 of the f32 row (o0..o7).
        // For each output j: partial over own 8 channels, butterfly over 32 lanes.
        float keep = 0.f;
        #pragma unroll
        for (int j = 0; j < 24; j++) {
            const float* vrow = V3 + j * HC + lloc * 8;
            float4 va = *(const float4*)vrow;
            float4 vb = *(const float4*)(vrow + 4);
            float p = o0 * va.x + o1 * va.y + o2 * va.z + o3 * va.w
                    + o4 * vb.x + o5 * vb.y + o6 * vb.z + o7 * vb.w;
            p += __shfl_xor(p, 1);
            p += __shfl_xor(p, 2);
            p += __shfl_xor(p, 4);
            p += __shfl_xor(p, 8);
            p += __shfl_xor(p, 16);
            if (lloc == j) keep = p;
        }
        if (lloc < 8)
            ((float*)q_out)[(size_t)(n * NHEAD + lloc) * 2] = keep;
        else if (lloc < 16)
            ((float*)q_out)[(size_t)(n * NHEAD + lloc - 8) * 2 + 1] = keep;
        else if (lloc < 24)
            ad3_out[n * NHEAD + lloc - 16] = keep;
    }
}

// ------- light gather (layer 3): thread per (dst,head), 8B per edge ---------
__global__ __launch_bounds__(256) void light_gather_kernel(
    const int* __restrict__ row_ptr, const int* __restrict__ esrc,
    const float2* __restrict__ q, const float* __restrict__ a_d,
    const float* __restrict__ bw, float* __restrict__ ndot)
{
    int idx = blockIdx.x * blockDim.x + threadIdx.x;
    if (idx >= N_NODES * NHEAD) return;
    int n = idx >> 3, hh = idx & 7;
    const float adv = a_d[idx];
    const int beg = row_ptr[n], end = row_ptr[n + 1];
    float acc = 0.f, den = 0.f;
    int e = beg;
    for (; e + 4 <= end; e += 4) {
        int s0 = esrc[e], s1 = esrc[e + 1], s2 = esrc[e + 2], s3 = esrc[e + 3];
        float2 q0 = q[s0 * NHEAD + hh];
        float2 q1 = q[s1 * NHEAD + hh];
        float2 q2 = q[s2 * NHEAD + hh];
        float2 q3 = q[s3 * NHEAD + hh];
        float t0 = q0.x + adv; t0 = (t0 > 0.f) ? t0 : 0.2f * t0; float w0 = __expf(t0);
        float t1 = q1.x + adv; t1 = (t1 > 0.f) ? t1 : 0.2f * t1; float w1 = __expf(t1);
        float t2 = q2.x + adv; t2 = (t2 > 0.f) ? t2 : 0.2f * t2; float w2 = __expf(t2);
        float t3 = q3.x + adv; t3 = (t3 > 0.f) ? t3 : 0.2f * t3; float w3 = __expf(t3);
        den += (w0 + w1) + (w2 + w3);
        acc = fmaf(w0, q0.y, acc); acc = fmaf(w1, q1.y, acc);
        acc = fmaf(w2, q2.y, acc); acc = fmaf(w3, q3.y, acc);
    }
    for (; e < end; e++) {
        int s = esrc[e];
        float2 qv = q[s * NHEAD + hh];
        float t = qv.x + adv; t = (t > 0.f) ? t : 0.2f * t;
        float w = __expf(t);
        den += w;
        acc = fmaf(w, qv.y, acc);
    }
    float p = acc / den + bw[hh];
    #pragma unroll
    for (int off = 4; off > 0; off >>= 1) p += __shfl_xor(p, off);
    if (hh == 0) ndot[n] = p;
}

// ------- per-graph mean over sorted batch (binary search, no atomics) -------
__global__ __launch_bounds__(256) void pool2_kernel(
    const float* __restrict__ ndot, const int* __restrict__ batch,
    const float* __restrict__ bf, float* __restrict__ outp)
{
    __shared__ float red[256];
    int g = blockIdx.x, t = threadIdx.x;
    int lo = 0, hi = N_NODES;
    while (lo < hi) { int mid = (lo + hi) >> 1; if (batch[mid] < g) lo = mid + 1; else hi = mid; }
    int start = lo;
    lo = 0; hi = N_NODES;
    while (lo < hi) { int mid = (lo + hi) >> 1; if (batch[mid] < g + 1) lo = mid + 1; else hi = mid; }
    int end = lo;
    float s = 0.f;
    for (int i = start + t; i < end; i += 256) s += ndot[i];
    red[t] = s;
    __syncthreads();
    for (int k = 128; k > 0; k >>= 1) {
        if (t < k) red[t] += red[t + k];
        __syncthreads();
    }
    if (t == 0) outp[g] = red[0] / fmaxf((float)(end - start), 1.f) + bf[0];
}

extern "C" void kernel_launch(void* const* d_in, const int* in_sizes, int n_in,
                              void* d_out, int out_size, void* d_ws, size_t ws_size,
                              hipStream_t stream)
{
    const float* x    = (const float*)d_in[0];
    const int*   ei   = (const int*)d_in[1];
    const int*   batch= (const int*)d_in[2];
    const float* W1   = (const float*)d_in[3];
    const float* as1  = (const float*)d_in[4];
    const float* ad1  = (const float*)d_in[5];
    const float* b1   = (const float*)d_in[6];
    const float* W2   = (const float*)d_in[7];
    const float* as2  = (const float*)d_in[8];
    const float* ad2  = (const float*)d_in[9];
    const float* b2   = (const float*)d_in[10];
    const float* W3   = (const float*)d_in[11];
    const float* as3  = (const float*)d_in[12];
    const float* ad3  = (const float*)d_in[13];
    const float* b3   = (const float*)d_in[14];
    const float* Wf   = (const float*)d_in[15];
    const float* bf   = (const float*)d_in[16];
    float* out = (float*)d_out;

    char* ws = (char*)d_ws;
    size_t off = 0;
    auto allocb = [&](size_t bytes) {
        void* p = ws + off;
        off += (bytes + 255) & ~(size_t)255;
        return p;
    };
    ushort* bufA    = (ushort*)allocb((size_t)N_NODES * HC * 2);
    ushort* bufB    = (ushort*)allocb((size_t)N_NODES * HC * 2);
    ushort* W1b     = (ushort*)allocb((size_t)HC * IN_CH * 2);
    ushort* W2b     = (ushort*)allocb((size_t)HC * HC * 2);
    ushort* W3b     = (ushort*)allocb((size_t)HC * HC * 2);
    ushort* Vb1     = (ushort*)allocb((size_t)16 * IN_CH * 2);
    ushort* Vb2     = (ushort*)allocb((size_t)16 * HC * 2);
    float*  V3f     = (float*) allocb((size_t)24 * HC * 4);
    float*  as_buf  = (float*) allocb((size_t)N_NODES * NHEAD * 4);
    float*  ad_buf  = (float*) allocb((size_t)N_NODES * NHEAD * 4);
    float2* q_buf   = (float2*)allocb((size_t)N_NODES * NHEAD * 8);
    float*  bw_buf  = (float*) allocb(NHEAD * 4);
    int*    deg     = (int*)   allocb(N_NODES * 4);      // deg+cur adjacent: one memset
    int*    cur     = (int*)   allocb(N_NODES * 4);
    int*    row_ptr = (int*)   allocb((N_NODES + 1) * 4);
    int*    csum    = (int*)   allocb(64 * 4);
    int*    esrc    = (int*)   allocb(E_EXT * 4);
    float*  ndot    = (float*) allocb(N_NODES * 4);
    (void)ws_size; (void)in_sizes; (void)n_in; (void)out_size;

    // ---- memset must precede prep (fused histogram) ----
    const size_t deg_pad = ((size_t)N_NODES * 4 + 255) & ~(size_t)255;
    hipMemsetAsync(deg, 0, deg_pad + (size_t)N_NODES * 4, stream);  // deg + cur

    // ---- prep: W cvt + composites + bw + hist ----
    prep_kernel<<<(PREP_TOT + 255) / 256, 256, 0, stream>>>(
        W1, W2, W3, W1b, W2b, W3b,
        as1, ad1, as2, ad2, as3, ad3, b3, Wf, bw_buf,
        Vb1, Vb2, V3f, ei, deg);

    // ---- CSR build ----
    scan1_kernel<<<N_CHUNKS, SCAN_CHUNK, 0, stream>>>(deg, row_ptr, csum);
    scan23_kernel<<<(N_NODES + 255) / 256, 256, 0, stream>>>(row_ptr, csum);
    scatter_kernel<<<(E_EXT + 255) / 256, 256, 0, stream>>>(ei, row_ptr, cur, esrc);

    dim3 ggrid((N_NODES + 127) / 128, HC / 128);
    const int gather_blocks = (((N_NODES + 1) / 2) * 64 + 255) / 256;

    // layer 1: x(f32) -> B(h1) + MFMA-epilogue(as/ad) -> A(h1')
    mfma_gemm_kernel<<<ggrid, 256, 0, stream>>>(
        nullptr, x, W1b, Vb1, bufB, N_NODES, IN_CH, as_buf, ad_buf);
    gather_kernel<<<gather_blocks, 256, 0, stream>>>(
        row_ptr, esrc, bufB, as_buf, ad_buf, b1, bufA,
        nullptr, nullptr, nullptr);
    // layer 2: A -> B(h2) + MFMA-epilogue(as/ad); gather-2 fuses layer-3 coeffs
    mfma_gemm_kernel<<<ggrid, 256, 0, stream>>>(
        bufA, nullptr, W2b, Vb2, bufB, N_NODES, HC, as_buf, ad_buf);
    gather_kernel<<<gather_blocks, 256, 0, stream>>>(
        row_ptr, esrc, bufB, as_buf, ad_buf, b2, nullptr,
        V3f, q_buf, ad_buf);
    // layer 3: light gather only
    light_gather_kernel<<<(N_NODES * NHEAD + 255) / 256, 256, 0, stream>>>(
        row_ptr, esrc, q_buf, ad_buf, bw_buf, ndot);

    pool2_kernel<<<NGRAPH, 256, 0, stream>>>(ndot, batch, bf, out);
}

// Round 15
// 304.243 us; speedup vs baseline: 1.0298x; 1.0298x over previous
//
#include <hip/hip_runtime.h>

#define N_NODES 50000
#define E_EDGES 800000
#define E_EXT   850000   // + self loops
#define IN_CH   128
#define HC      256
#define NHEAD   8
#define CH      32
#define NGRAPH  256
#define SCAN_CHUNK 1024
#define N_CHUNKS ((N_NODES + SCAN_CHUNK - 1) / SCAN_CHUNK)

typedef __bf16 bf16x8 __attribute__((ext_vector_type(8)));
typedef float  f32x4  __attribute__((ext_vector_type(4)));

__device__ inline ushort f2bf(float f) {
    union { float f; unsigned u; } v; v.f = f;
    unsigned u = v.u;
    unsigned r = u + 0x7FFFu + ((u >> 16) & 1u);
    return (ushort)(r >> 16);
}
__device__ inline float bflo(unsigned u) {
    union { unsigned u; float f; } v; v.u = u << 16; return v.f;
}
__device__ inline float bfhi(unsigned u) {
    union { unsigned u; float f; } v; v.u = u & 0xFFFF0000u; return v.f;
}

// ---- prep: W cvt + composite V matrices + bw + edge histogram (fused) ------
// Vb1[16][128]: rows 0-7 = W1_h^T as1_h, 8-15 = W1_h^T ad1_h
// Vb2[16][256]: same for layer 2
// Vb3[32][256]: rows 0-7 = W3^T as3, 8-15 = W3^T Wf, 16-23 = W3^T ad3, 24-31 = 0
#define W1_N4 (HC * IN_CH / 4)            // 8192
#define W23_N4 (HC * HC / 4)              // 16384
#define CVT_N4 (W1_N4 + 2 * W23_N4)       // 40960
#define V1_N  (16 * IN_CH)                // 2048
#define V2_N  (16 * HC)                   // 4096
#define V3_N  (32 * HC)                   // 8192
#define COMP_TOT (V1_N + V2_N + V3_N)
#define PREP_TOT (CVT_N4 + COMP_TOT + E_EXT)
__global__ __launch_bounds__(256) void prep_kernel(
    const float* __restrict__ W1, const float* __restrict__ W2,
    const float* __restrict__ W3,
    ushort* __restrict__ W1b, ushort* __restrict__ W2b, ushort* __restrict__ W3b,
    const float* __restrict__ as1, const float* __restrict__ ad1,
    const float* __restrict__ as2, const float* __restrict__ ad2,
    const float* __restrict__ as3, const float* __restrict__ ad3,
    const float* __restrict__ b3, const float* __restrict__ Wf,
    float* __restrict__ bw,
    ushort* __restrict__ Vb1, ushort* __restrict__ Vb2, ushort* __restrict__ Vb3,
    const int* __restrict__ ei, int* __restrict__ deg)
{
    int i = blockIdx.x * blockDim.x + threadIdx.x;
    if (blockIdx.x == 0 && threadIdx.x < NHEAD) {
        float s = 0.f;
        for (int c = 0; c < CH; c++)
            s += b3[threadIdx.x * CH + c] * Wf[threadIdx.x * CH + c];
        bw[threadIdx.x] = s;
    }
    if (i < CVT_N4) {
        const float* src; ushort* dst; int k;
        if (i < W1_N4) { src = W1; dst = W1b; k = i; }
        else if (i < W1_N4 + W23_N4) { src = W2; dst = W2b; k = i - W1_N4; }
        else { src = W3; dst = W3b; k = i - W1_N4 - W23_N4; }
        float4 v = *(const float4*)(src + (size_t)k * 4);
        ushort4 o;
        o.x = f2bf(v.x); o.y = f2bf(v.y); o.z = f2bf(v.z); o.w = f2bf(v.w);
        *(ushort4*)(dst + (size_t)k * 4) = o;
        return;
    }
    int c2 = i - CVT_N4;
    if (c2 < V1_N + V2_N) {
        const float* Wsrc; const float* aw; ushort* dst; int F_, j, k;
        if (c2 < V1_N) {
            F_ = IN_CH; j = c2 >> 7; k = c2 & 127; Wsrc = W1; dst = Vb1;
            aw = (j < 8) ? as1 : ad1;
        } else {
            c2 -= V1_N;
            F_ = HC; j = c2 >> 8; k = c2 & 255; Wsrc = W2; dst = Vb2;
            aw = (j < 8) ? as2 : ad2;
        }
        int h = j & 7;
        float v = 0.f;
        for (int c = 0; c < CH; c++)
            v += aw[h * CH + c] * Wsrc[(size_t)(h * CH + c) * F_ + k];
        dst[j * F_ + k] = f2bf(v);
        return;
    }
    c2 -= V1_N + V2_N;
    if (c2 < V3_N) {
        int j = c2 >> 8, k = c2 & 255;
        float v = 0.f;
        if (j < 24) {
            int h = j & 7;
            const float* aw = (j < 8) ? as3 : (j < 16 ? Wf : ad3);
            for (int c = 0; c < CH; c++)
                v += aw[h * CH + c] * W3[(size_t)(h * CH + c) * HC + k];
        }
        Vb3[j * HC + k] = f2bf(v);
        return;
    }
    int e = i - CVT_N4 - COMP_TOT;
    if (e < E_EXT) {
        int d = (e < E_EDGES) ? ei[E_EDGES + e] : (e - E_EDGES);
        atomicAdd(&deg[d], 1);
    }
}

// ------- MFMA GEMM 128x128 tile + MFMA attention epilogue (template F) ------
// blockIdx.y==0 even waves also compute [rows x 16] = A @ Vb[0:16]^T:
// col fr<8 -> a_s[m][fr], fr>=8 -> a_d[m][fr-8].
template <int F>
__global__ __launch_bounds__(256) void mfma_gemm_kernel(
    const ushort* __restrict__ Xb, const float* __restrict__ Xf,
    const ushort* __restrict__ Wb, const ushort* __restrict__ Vb,
    ushort* __restrict__ Hb, int M,
    float* __restrict__ as_out, float* __restrict__ ad_out)
{
    __shared__ ushort As[128][40];
    __shared__ ushort Bs[128][40];
    __shared__ ushort Vs[16][40];
    const int tid  = threadIdx.x;
    const int lane = tid & 63;
    const int wave = tid >> 6;
    const int wr = (wave >> 1) * 64;
    const int wc = (wave & 1) * 64;
    const int bm = blockIdx.x * 128;
    const int bn = blockIdx.y * 128;
    const int lrow = tid >> 2;
    const int lseg = (tid & 3) * 8;
    const int fr = lane & 15;
    const int fk = (lane >> 4) * 8;
    const bool doV = (blockIdx.y == 0) && !(wave & 1);

    f32x4 zero = {0.f, 0.f, 0.f, 0.f};
    f32x4 acc[4][4];
    f32x4 accv[4];
    #pragma unroll
    for (int i = 0; i < 4; i++) {
        accv[i] = zero;
        #pragma unroll
        for (int j = 0; j < 4; j++) acc[i][j] = zero;
    }

    #pragma unroll
    for (int k0 = 0; k0 < F; k0 += 32) {
        #pragma unroll
        for (int rr = 0; rr < 2; rr++) {
            int row = lrow + rr * 64;
            int arow = bm + row;
            bf16x8 av = {};
            if (Xf) {
                if (arow < M) {
                    float4 lo = *(const float4*)(Xf + (size_t)arow * F + k0 + lseg);
                    float4 hi = *(const float4*)(Xf + (size_t)arow * F + k0 + lseg + 4);
                    ushort t[8] = { f2bf(lo.x), f2bf(lo.y), f2bf(lo.z), f2bf(lo.w),
                                    f2bf(hi.x), f2bf(hi.y), f2bf(hi.z), f2bf(hi.w) };
                    av = *(const bf16x8*)t;
                }
            } else {
                if (arow < M) av = *(const bf16x8*)(Xb + (size_t)arow * F + k0 + lseg);
            }
            *(bf16x8*)(&As[row][lseg]) = av;
            bf16x8 bv = *(const bf16x8*)(Wb + (size_t)(bn + row) * F + k0 + lseg);
            *(bf16x8*)(&Bs[row][lseg]) = bv;
        }
        if (tid < 64) {
            int vr = tid >> 2;
            *(bf16x8*)(&Vs[vr][lseg]) = *(const bf16x8*)(Vb + (size_t)vr * F + k0 + lseg);
        }
        __syncthreads();
        bf16x8 a[4], b[4];
        #pragma unroll
        for (int i = 0; i < 4; i++) {
            a[i] = *(const bf16x8*)(&As[wr + i * 16 + fr][fk]);
            b[i] = *(const bf16x8*)(&Bs[wc + i * 16 + fr][fk]);
        }
        #pragma unroll
        for (int i = 0; i < 4; i++)
            #pragma unroll
            for (int j = 0; j < 4; j++)
                acc[i][j] = __builtin_amdgcn_mfma_f32_16x16x32_bf16(
                    a[i], b[j], acc[i][j], 0, 0, 0);
        if (doV) {
            bf16x8 bv = *(const bf16x8*)(&Vs[fr][fk]);
            #pragma unroll
            for (int i = 0; i < 4; i++)
                accv[i] = __builtin_amdgcn_mfma_f32_16x16x32_bf16(
                    a[i], bv, accv[i], 0, 0, 0);
        }
        __syncthreads();
    }
    const int rb = (lane >> 4) * 4;
    #pragma unroll
    for (int i = 0; i < 4; i++) {
        #pragma unroll
        for (int r = 0; r < 4; r++) {
            int m = bm + wr + i * 16 + rb + r;
            if (m < M) {
                #pragma unroll
                for (int j = 0; j < 4; j++)
                    Hb[(size_t)m * HC + bn + wc + j * 16 + fr] = f2bf(acc[i][j][r]);
            }
        }
    }
    if (doV) {
        #pragma unroll
        for (int i = 0; i < 4; i++) {
            #pragma unroll
            for (int r = 0; r < 4; r++) {
                int m = bm + wr + i * 16 + rb + r;
                if (m < M) {
                    float v = accv[i][r];
                    if (fr < 8) as_out[m * NHEAD + fr] = v;
                    else        ad_out[m * NHEAD + fr - 8] = v;
                }
            }
        }
    }
}

// ------- thin MFMA GEMM (layer 3): [M,HC] @ Vb3[32][HC]^T -> q/a_d ----------
// col jj<8 -> q[m][jj].x (a_s); 8..15 -> q.y (hw); 16..23 -> a_d
__global__ __launch_bounds__(256) void thin_gemm_kernel(
    const ushort* __restrict__ Xb, const ushort* __restrict__ Vb, int M,
    float2* __restrict__ q_out, float* __restrict__ ad_out)
{
    __shared__ ushort As[128][40];
    __shared__ ushort Bs[32][40];
    const int tid  = threadIdx.x;
    const int lane = tid & 63;
    const int wave = tid >> 6;
    const int bm = blockIdx.x * 128;
    const int lrow = tid >> 2;
    const int lseg = (tid & 3) * 8;
    const int fr = lane & 15;
    const int fk = (lane >> 4) * 8;

    f32x4 zero = {0.f, 0.f, 0.f, 0.f};
    f32x4 acc[2][2];
    #pragma unroll
    for (int i = 0; i < 2; i++)
        #pragma unroll
        for (int j = 0; j < 2; j++) acc[i][j] = zero;

    #pragma unroll
    for (int k0 = 0; k0 < HC; k0 += 32) {
        #pragma unroll
        for (int rr = 0; rr < 2; rr++) {
            int row = lrow + rr * 64;
            int arow = bm + row;
            bf16x8 av = {};
            if (arow < M) av = *(const bf16x8*)(Xb + (size_t)arow * HC + k0 + lseg);
            *(bf16x8*)(&As[row][lseg]) = av;
        }
        if (tid < 128) {
            int brow = tid >> 2;
            bf16x8 bv = *(const bf16x8*)(Vb + (size_t)brow * HC + k0 + lseg);
            *(bf16x8*)(&Bs[brow][lseg]) = bv;
        }
        __syncthreads();
        bf16x8 a[2], b[2];
        #pragma unroll
        for (int i = 0; i < 2; i++)
            a[i] = *(const bf16x8*)(&As[wave * 32 + i * 16 + fr][fk]);
        b[0] = *(const bf16x8*)(&Bs[fr][fk]);
        b[1] = *(const bf16x8*)(&Bs[16 + fr][fk]);
        #pragma unroll
        for (int i = 0; i < 2; i++)
            #pragma unroll
            for (int j = 0; j < 2; j++)
                acc[i][j] = __builtin_amdgcn_mfma_f32_16x16x32_bf16(
                    a[i], b[j], acc[i][j], 0, 0, 0);
        __syncthreads();
    }

    const int rb = (lane >> 4) * 4;
    #pragma unroll
    for (int i = 0; i < 2; i++) {
        #pragma unroll
        for (int r = 0; r < 4; r++) {
            int m = bm + wave * 32 + i * 16 + rb + r;
            if (m >= M) continue;
            #pragma unroll
            for (int j = 0; j < 2; j++) {
                int jj = j * 16 + fr;
                float v = acc[i][j][r];
                if (jj < 8)       ((float*)q_out)[(size_t)(m * NHEAD + jj) * 2] = v;
                else if (jj < 16) ((float*)q_out)[(size_t)(m * NHEAD + jj - 8) * 2 + 1] = v;
                else if (jj < 24) ad_out[m * NHEAD + jj - 16] = v;
            }
        }
    }
}

// ---------------- CSR build ----------------
__global__ void scan1_kernel(const int* __restrict__ deg,
                             int* __restrict__ row_ptr, int* __restrict__ csum)
{
    __shared__ int buf[SCAN_CHUNK];
    int t = threadIdx.x;
    int base = blockIdx.x * SCAN_CHUNK;
    int v = (base + t < N_NODES) ? deg[base + t] : 0;
    buf[t] = v;
    __syncthreads();
    for (int off = 1; off < SCAN_CHUNK; off <<= 1) {
        int x = buf[t];
        int y = (t >= off) ? buf[t - off] : 0;
        __syncthreads();
        buf[t] = x + y;
        __syncthreads();
    }
    if (base + t < N_NODES) row_ptr[base + t] = buf[t] - v;
    if (t == SCAN_CHUNK - 1) csum[blockIdx.x] = buf[t];
}

__global__ __launch_bounds__(256) void scan23_kernel(
    int* __restrict__ row_ptr, const int* __restrict__ csum)
{
    __shared__ int pref[64];
    int t = threadIdx.x;
    int i = blockIdx.x * blockDim.x + t;
    if (t < 64) pref[t] = (t < N_CHUNKS) ? csum[t] : 0;
    __syncthreads();
    for (int off = 1; off < 64; off <<= 1) {
        int x = 0, y = 0;
        if (t < 64) { x = pref[t]; y = (t >= off) ? pref[t - off] : 0; }
        __syncthreads();
        if (t < 64) pref[t] = x + y;   // inclusive
        __syncthreads();
    }
    if (i < N_NODES) {
        int ch = i / SCAN_CHUNK;
        row_ptr[i] += (ch > 0) ? pref[ch - 1] : 0;
    }
    if (i == 0) row_ptr[N_NODES] = E_EXT;
}

__global__ __launch_bounds__(256) void scatter_kernel(
    const int* __restrict__ ei, const int* __restrict__ row_ptr,
    int* __restrict__ cur, int* __restrict__ esrc)
{
    int eid = blockIdx.x * blockDim.x + threadIdx.x;
    if (eid >= E_EXT) return;
    int s, d;
    if (eid < E_EDGES) { s = ei[eid]; d = ei[E_EDGES + eid]; }
    else { s = eid - E_EDGES; d = s; }
    int pos = row_ptr[d] + atomicAdd(&cur[d], 1);
    esrc[pos] = s;
}

// ------- heavy gather: 2 dst/wave, 8 ch/lane, 4-deep pipeline ---------------
__global__ __launch_bounds__(256) void gather_kernel(
    const int* __restrict__ row_ptr, const int* __restrict__ esrc,
    const ushort* __restrict__ hb,
    const float* __restrict__ a_s, const float* __restrict__ a_d,
    const float* __restrict__ bias,
    ushort* __restrict__ out_b)
{
    int wv = (blockIdx.x * blockDim.x + threadIdx.x) >> 6;
    int lane = threadIdx.x & 63;
    int half = lane >> 5;
    int lloc = lane & 31;
    int n = wv * 2 + half;
    if (n >= N_NODES) return;
    const int hh = lloc >> 2;
    const int shbase = half << 5;
    const float adv = a_d[n * NHEAD + hh];
    const int beg = row_ptr[n], end = row_ptr[n + 1];

    float a0=0.f,a1=0.f,a2=0.f,a3=0.f,a4=0.f,a5=0.f,a6=0.f,a7=0.f,den=0.f;

    for (int base = beg; base < end; base += 32) {
        int cnt = min(32, end - base);
        int sv = (base + lloc < end) ? esrc[base + lloc] : 0;
        int j = 0;
        for (; j + 4 <= cnt; j += 4) {
            int s0 = __shfl(sv, shbase + j);
            int s1 = __shfl(sv, shbase + j + 1);
            int s2 = __shfl(sv, shbase + j + 2);
            int s3 = __shfl(sv, shbase + j + 3);
            float e0 = a_s[s0 * NHEAD + hh];
            float e1 = a_s[s1 * NHEAD + hh];
            float e2 = a_s[s2 * NHEAD + hh];
            float e3 = a_s[s3 * NHEAD + hh];
            uint4 u0 = *(const uint4*)(hb + (size_t)s0 * HC + lloc * 8);
            uint4 u1 = *(const uint4*)(hb + (size_t)s1 * HC + lloc * 8);
            uint4 u2 = *(const uint4*)(hb + (size_t)s2 * HC + lloc * 8);
            uint4 u3 = *(const uint4*)(hb + (size_t)s3 * HC + lloc * 8);
            e0 += adv; e0 = (e0 > 0.f) ? e0 : 0.2f * e0; float w0 = __expf(e0);
            e1 += adv; e1 = (e1 > 0.f) ? e1 : 0.2f * e1; float w1 = __expf(e1);
            e2 += adv; e2 = (e2 > 0.f) ? e2 : 0.2f * e2; float w2 = __expf(e2);
            e3 += adv; e3 = (e3 > 0.f) ? e3 : 0.2f * e3; float w3 = __expf(e3);
            den += (w0 + w1) + (w2 + w3);
            a0 = fmaf(w0, bflo(u0.x), a0); a1 = fmaf(w0, bfhi(u0.x), a1);
            a2 = fmaf(w0, bflo(u0.y), a2); a3 = fmaf(w0, bfhi(u0.y), a3);
            a4 = fmaf(w0, bflo(u0.z), a4); a5 = fmaf(w0, bfhi(u0.z), a5);
            a6 = fmaf(w0, bflo(u0.w), a6); a7 = fmaf(w0, bfhi(u0.w), a7);
            a0 = fmaf(w1, bflo(u1.x), a0); a1 = fmaf(w1, bfhi(u1.x), a1);
            a2 = fmaf(w1, bflo(u1.y), a2); a3 = fmaf(w1, bfhi(u1.y), a3);
            a4 = fmaf(w1, bflo(u1.z), a4); a5 = fmaf(w1, bfhi(u1.z), a5);
            a6 = fmaf(w1, bflo(u1.w), a6); a7 = fmaf(w1, bfhi(u1.w), a7);
            a0 = fmaf(w2, bflo(u2.x), a0); a1 = fmaf(w2, bfhi(u2.x), a1);
            a2 = fmaf(w2, bflo(u2.y), a2); a3 = fmaf(w2, bfhi(u2.y), a3);
            a4 = fmaf(w2, bflo(u2.z), a4); a5 = fmaf(w2, bfhi(u2.z), a5);
            a6 = fmaf(w2, bflo(u2.w), a6); a7 = fmaf(w2, bfhi(u2.w), a7);
            a0 = fmaf(w3, bflo(u3.x), a0); a1 = fmaf(w3, bfhi(u3.x), a1);
            a2 = fmaf(w3, bflo(u3.y), a2); a3 = fmaf(w3, bfhi(u3.y), a3);
            a4 = fmaf(w3, bflo(u3.z), a4); a5 = fmaf(w3, bfhi(u3.z), a5);
            a6 = fmaf(w3, bflo(u3.w), a6); a7 = fmaf(w3, bfhi(u3.w), a7);
        }
        for (; j < cnt; j++) {
            int s = __shfl(sv, shbase + j);
            float e = a_s[s * NHEAD + hh] + adv;
            e = (e > 0.f) ? e : 0.2f * e;
            float w = __expf(e);
            den += w;
            uint4 u = *(const uint4*)(hb + (size_t)s * HC + lloc * 8);
            a0 = fmaf(w, bflo(u.x), a0); a1 = fmaf(w, bfhi(u.x), a1);
            a2 = fmaf(w, bflo(u.y), a2); a3 = fmaf(w, bfhi(u.y), a3);
            a4 = fmaf(w, bflo(u.z), a4); a5 = fmaf(w, bfhi(u.z), a5);
            a6 = fmaf(w, bflo(u.w), a6); a7 = fmaf(w, bfhi(u.w), a7);
        }
    }
    float inv = 1.f / den;
    float4 ba = *(const float4*)(bias + lloc * 8);
    float4 bb = *(const float4*)(bias + lloc * 8 + 4);
    float o0 = fmaf(a0, inv, ba.x), o1 = fmaf(a1, inv, ba.y);
    float o2 = fmaf(a2, inv, ba.z), o3 = fmaf(a3, inv, ba.w);
    float o4 = fmaf(a4, inv, bb.x), o5 = fmaf(a5, inv, bb.y);
    float o6 = fmaf(a6, inv, bb.z), o7 = fmaf(a7, inv, bb.w);
    o0 = fmaxf(o0, 0.f); o1 = fmaxf(o1, 0.f); o2 = fmaxf(o2, 0.f); o3 = fmaxf(o3, 0.f);
    o4 = fmaxf(o4, 0.f); o5 = fmaxf(o5, 0.f); o6 = fmaxf(o6, 0.f); o7 = fmaxf(o7, 0.f);
    uint4 ob;
    ob.x = (unsigned)f2bf(o0) | ((unsigned)f2bf(o1) << 16);
    ob.y = (unsigned)f2bf(o2) | ((unsigned)f2bf(o3) << 16);
    ob.z = (unsigned)f2bf(o4) | ((unsigned)f2bf(o5) << 16);
    ob.w = (unsigned)f2bf(o6) | ((unsigned)f2bf(o7) << 16);
    *(uint4*)(out_b + (size_t)n * HC + lloc * 8) = ob;
}

// ------- light gather (layer 3): thread per (dst,head), 8B per edge ---------
__global__ __launch_bounds__(256) void light_gather_kernel(
    const int* __restrict__ row_ptr, const int* __restrict__ esrc,
    const float2* __restrict__ q, const float* __restrict__ a_d,
    const float* __restrict__ bw, float* __restrict__ ndot)
{
    int idx = blockIdx.x * blockDim.x + threadIdx.x;
    if (idx >= N_NODES * NHEAD) return;
    int n = idx >> 3, hh = idx & 7;
    const float adv = a_d[idx];
    const int beg = row_ptr[n], end = row_ptr[n + 1];
    float acc = 0.f, den = 0.f;
    int e = beg;
    for (; e + 4 <= end; e += 4) {
        int s0 = esrc[e], s1 = esrc[e + 1], s2 = esrc[e + 2], s3 = esrc[e + 3];
        float2 q0 = q[s0 * NHEAD + hh];
        float2 q1 = q[s1 * NHEAD + hh];
        float2 q2 = q[s2 * NHEAD + hh];
        float2 q3 = q[s3 * NHEAD + hh];
        float t0 = q0.x + adv; t0 = (t0 > 0.f) ? t0 : 0.2f * t0; float w0 = __expf(t0);
        float t1 = q1.x + adv; t1 = (t1 > 0.f) ? t1 : 0.2f * t1; float w1 = __expf(t1);
        float t2 = q2.x + adv; t2 = (t2 > 0.f) ? t2 : 0.2f * t2; float w2 = __expf(t2);
        float t3 = q3.x + adv; t3 = (t3 > 0.f) ? t3 : 0.2f * t3; float w3 = __expf(t3);
        den += (w0 + w1) + (w2 + w3);
        acc = fmaf(w0, q0.y, acc); acc = fmaf(w1, q1.y, acc);
        acc = fmaf(w2, q2.y, acc); acc = fmaf(w3, q3.y, acc);
    }
    for (; e < end; e++) {
        int s = esrc[e];
        float2 qv = q[s * NHEAD + hh];
        float t = qv.x + adv; t = (t > 0.f) ? t : 0.2f * t;
        float w = __expf(t);
        den += w;
        acc = fmaf(w, qv.y, acc);
    }
    float p = acc / den + bw[hh];
    #pragma unroll
    for (int off = 4; off > 0; off >>= 1) p += __shfl_xor(p, off);
    if (hh == 0) ndot[n] = p;
}

// ------- per-graph mean over sorted batch (binary search, no atomics) -------
__global__ __launch_bounds__(256) void pool2_kernel(
    const float* __restrict__ ndot, const int* __restrict__ batch,
    const float* __restrict__ bf, float* __restrict__ outp)
{
    __shared__ float red[256];
    int g = blockIdx.x, t = threadIdx.x;
    int lo = 0, hi = N_NODES;
    while (lo < hi) { int mid = (lo + hi) >> 1; if (batch[mid] < g) lo = mid + 1; else hi = mid; }
    int start = lo;
    lo = 0; hi = N_NODES;
    while (lo < hi) { int mid = (lo + hi) >> 1; if (batch[mid] < g + 1) lo = mid + 1; else hi = mid; }
    int end = lo;
    float s = 0.f;
    for (int i = start + t; i < end; i += 256) s += ndot[i];
    red[t] = s;
    __syncthreads();
    for (int k = 128; k > 0; k >>= 1) {
        if (t < k) red[t] += red[t + k];
        __syncthreads();
    }
    if (t == 0) outp[g] = red[0] / fmaxf((float)(end - start), 1.f) + bf[0];
}

extern "C" void kernel_launch(void* const* d_in, const int* in_sizes, int n_in,
                              void* d_out, int out_size, void* d_ws, size_t ws_size,
                              hipStream_t stream)
{
    const float* x    = (const float*)d_in[0];
    const int*   ei   = (const int*)d_in[1];
    const int*   batch= (const int*)d_in[2];
    const float* W1   = (const float*)d_in[3];
    const float* as1  = (const float*)d_in[4];
    const float* ad1  = (const float*)d_in[5];
    const float* b1   = (const float*)d_in[6];
    const float* W2   = (const float*)d_in[7];
    const float* as2  = (const float*)d_in[8];
    const float* ad2  = (const float*)d_in[9];
    const float* b2   = (const float*)d_in[10];
    const float* W3   = (const float*)d_in[11];
    const float* as3  = (const float*)d_in[12];
    const float* ad3  = (const float*)d_in[13];
    const float* b3   = (const float*)d_in[14];
    const float* Wf   = (const float*)d_in[15];
    const float* bf   = (const float*)d_in[16];
    float* out = (float*)d_out;

    char* ws = (char*)d_ws;
    size_t off = 0;
    auto allocb = [&](size_t bytes) {
        void* p = ws + off;
        off += (bytes + 255) & ~(size_t)255;
        return p;
    };
    ushort* bufA    = (ushort*)allocb((size_t)N_NODES * HC * 2);
    ushort* bufB    = (ushort*)allocb((size_t)N_NODES * HC * 2);
    ushort* W1b     = (ushort*)allocb((size_t)HC * IN_CH * 2);
    ushort* W2b     = (ushort*)allocb((size_t)HC * HC * 2);
    ushort* W3b     = (ushort*)allocb((size_t)HC * HC * 2);
    ushort* Vb1     = (ushort*)allocb((size_t)16 * IN_CH * 2);
    ushort* Vb2     = (ushort*)allocb((size_t)16 * HC * 2);
    ushort* Vb3     = (ushort*)allocb((size_t)32 * HC * 2);
    float*  as_buf  = (float*) allocb((size_t)N_NODES * NHEAD * 4);
    float*  ad_buf  = (float*) allocb((size_t)N_NODES * NHEAD * 4);
    float2* q_buf   = (float2*)allocb((size_t)N_NODES * NHEAD * 8);
    float*  bw_buf  = (float*) allocb(NHEAD * 4);
    int*    deg     = (int*)   allocb(N_NODES * 4);      // deg+cur adjacent: one memset
    int*    cur     = (int*)   allocb(N_NODES * 4);
    int*    row_ptr = (int*)   allocb((N_NODES + 1) * 4);
    int*    csum    = (int*)   allocb(64 * 4);
    int*    esrc    = (int*)   allocb(E_EXT * 4);
    float*  ndot    = (float*) allocb(N_NODES * 4);
    (void)ws_size; (void)in_sizes; (void)n_in; (void)out_size;

    // ---- memset must precede prep (fused histogram) ----
    const size_t deg_pad = ((size_t)N_NODES * 4 + 255) & ~(size_t)255;
    hipMemsetAsync(deg, 0, deg_pad + (size_t)N_NODES * 4, stream);  // deg + cur

    // ---- prep: W cvt + composites + bw + hist ----
    prep_kernel<<<(PREP_TOT + 255) / 256, 256, 0, stream>>>(
        W1, W2, W3, W1b, W2b, W3b,
        as1, ad1, as2, ad2, as3, ad3, b3, Wf, bw_buf,
        Vb1, Vb2, Vb3, ei, deg);

    // ---- CSR build ----
    scan1_kernel<<<N_CHUNKS, SCAN_CHUNK, 0, stream>>>(deg, row_ptr, csum);
    scan23_kernel<<<(N_NODES + 255) / 256, 256, 0, stream>>>(row_ptr, csum);
    scatter_kernel<<<(E_EXT + 255) / 256, 256, 0, stream>>>(ei, row_ptr, cur, esrc);

    dim3 ggrid((N_NODES + 127) / 128, HC / 128);
    const int gather_blocks = (((N_NODES + 1) / 2) * 64 + 255) / 256;
    const int thin_blocks = (N_NODES + 127) / 128;

    // layer 1: x(f32) -> B(h1) + MFMA-epilogue(as/ad) -> A(h1')
    mfma_gemm_kernel<IN_CH><<<ggrid, 256, 0, stream>>>(
        nullptr, x, W1b, Vb1, bufB, N_NODES, as_buf, ad_buf);
    gather_kernel<<<gather_blocks, 256, 0, stream>>>(
        row_ptr, esrc, bufB, as_buf, ad_buf, b1, bufA);
    // layer 2: A -> B(h2) + MFMA-epilogue(as/ad) -> A
    mfma_gemm_kernel<HC><<<ggrid, 256, 0, stream>>>(
        bufA, nullptr, W2b, Vb2, bufB, N_NODES, as_buf, ad_buf);
    gather_kernel<<<gather_blocks, 256, 0, stream>>>(
        row_ptr, esrc, bufB, as_buf, ad_buf, b2, bufA);
    // layer 3: thin GEMM -> q/a_d, then light gather
    thin_gemm_kernel<<<thin_blocks, 256, 0, stream>>>(
        bufA, Vb3, N_NODES, q_buf, ad_buf);
    light_gather_kernel<<<(N_NODES * NHEAD + 255) / 256, 256, 0, stream>>>(
        row_ptr, esrc, q_buf, ad_buf, bw_buf, ndot);

    pool2_kernel<<<NGRAPH, 256, 0, stream>>>(ndot, batch, bf, out);
}